// Round 3
// baseline (320.703 us; speedup 1.0000x reference)
//
#include <hip/hip_runtime.h>
#include <hip/hip_bf16.h>
#include <cstdint>
#include <cstddef>

typedef float  f32x4  __attribute__((ext_vector_type(4)));
typedef __bf16 bf16x8 __attribute__((ext_vector_type(8)));
typedef __bf16 bf16x4 __attribute__((ext_vector_type(4)));

#define HIDDEN 1024
#define SEQ    2048
#define BATCH  2
#define NQKV   3072
#define MTOT   4096

__device__ __forceinline__ __bf16 f2bf(float f) {
  unsigned u = __builtin_bit_cast(unsigned, f);
  u += 0x7FFFu + ((u >> 16) & 1u);          // round-to-nearest-even
  unsigned short s = (unsigned short)(u >> 16);
  return __builtin_bit_cast(__bf16, s);
}

__device__ __forceinline__ float fexp2(float x) {
#if __has_builtin(__builtin_amdgcn_exp2f)
  return __builtin_amdgcn_exp2f(x);   // bare v_exp_f32, ~1 ULP
#else
  return exp2f(x);
#endif
}

__device__ __forceinline__ void async16(const void* g, void* l) {
  __builtin_amdgcn_global_load_lds((__attribute__((address_space(1))) void*)(g),
                                   (__attribute__((address_space(3))) void*)(l),
                                   16, 0, 0);
}

// ---------------- fp32 -> bf16 elementwise convert (x) ----------------
__global__ __launch_bounds__(256) void k_convert_x(const float* __restrict__ in,
                                                   __bf16* __restrict__ out) {
  int i = blockIdx.x * 256 + threadIdx.x;
  float4 v = ((const float4*)in)[i];
  bf16x4 o;
  o[0] = f2bf(v.x); o[1] = f2bf(v.y); o[2] = f2bf(v.z); o[3] = f2bf(v.w);
  ((bf16x4*)out)[i] = o;
}

// ---------------- W[K][N] fp32 -> WT[N][K] bf16 ----------------
__global__ __launch_bounds__(256) void k_transpose_w(const float* __restrict__ W,
                                                     __bf16* __restrict__ WT,
                                                     int K, int N) {
  __shared__ float tile[64][65];
  int tx = threadIdx.x & 63, ty = threadIdx.x >> 6;
  int n0 = blockIdx.x * 64, k0 = blockIdx.y * 64;
#pragma unroll
  for (int r = 0; r < 16; r++) {
    int row = r * 4 + ty;
    tile[row][tx] = W[(size_t)(k0 + row) * N + n0 + tx];
  }
  __syncthreads();
#pragma unroll
  for (int r = 0; r < 16; r++) {
    int row = r * 4 + ty;   // n index
    WT[(size_t)(n0 + row) * K + k0 + tx] = f2bf(tile[tx][row]);
  }
}

// ---------------- GEMM: C[M][N] = A[M][K] * BT[N][K]^T + bias ----------------
template <int BF16OUT>
__global__ __launch_bounds__(256) void k_gemm(const __bf16* __restrict__ A,
                                              const __bf16* __restrict__ BT,
                                              const float* __restrict__ bias,
                                              void* __restrict__ Cout,
                                              int M, int N, int K) {
  __shared__ __align__(16) __bf16 As[128 * 32];
  __shared__ __align__(16) __bf16 Bs[128 * 32];
  const int t = threadIdx.x;
  const int lane = t & 63, wv = t >> 6;
  const int ln = lane & 15, quad = lane >> 4;
  const int wm = (wv & 1) * 64, wn = (wv >> 1) * 64;
  const int m0 = blockIdx.y * 128, n0 = blockIdx.x * 128;

  const f32x4 zero4 = {0.f, 0.f, 0.f, 0.f};
  f32x4 acc[4][4];
#pragma unroll
  for (int i = 0; i < 4; i++)
#pragma unroll
    for (int j = 0; j < 4; j++) acc[i][j] = zero4;

  for (int k0 = 0; k0 < K; k0 += 32) {
    __syncthreads();
#pragma unroll
    for (int i = 0; i < 2; i++) {
      int tt = i * 256 + t;
      int row = tt >> 2, ch = tt & 3;
      async16(A  + (size_t)(m0 + row) * K + k0 + ch * 8, As + tt * 8);
      async16(BT + (size_t)(n0 + row) * K + k0 + ch * 8, Bs + tt * 8);
    }
    __syncthreads();
    bf16x8 af[4], bfr[4];
#pragma unroll
    for (int x = 0; x < 4; x++)
      af[x] = *(const bf16x8*)(As + (wm + x * 16 + ln) * 32 + quad * 8);
#pragma unroll
    for (int x = 0; x < 4; x++)
      bfr[x] = *(const bf16x8*)(Bs + (wn + x * 16 + ln) * 32 + quad * 8);
#pragma unroll
    for (int mt = 0; mt < 4; mt++)
#pragma unroll
      for (int nt = 0; nt < 4; nt++)
        acc[mt][nt] = __builtin_amdgcn_mfma_f32_16x16x32_bf16(af[mt], bfr[nt], acc[mt][nt], 0, 0, 0);
  }
#pragma unroll
  for (int nt = 0; nt < 4; nt++) {
    int col = n0 + wn + nt * 16 + ln;
    float bv = bias[col];
#pragma unroll
    for (int mt = 0; mt < 4; mt++) {
#pragma unroll
      for (int r = 0; r < 4; r++) {
        int row = m0 + wm + mt * 16 + quad * 4 + r;
        float v = acc[mt][nt][r] + bv;
        if (BF16OUT) ((__bf16*)Cout)[(size_t)row * N + col] = f2bf(v);
        else         ((float*)Cout)[(size_t)row * N + col] = v;
      }
    }
  }
}

// ---------------- V slice of qkv -> vt[bh][d=64][s' permuted] ----------------
// Within each 128-wide s-block: s' = (s&15)*8 + (s>>4)  (matches P-store layout
// in k_attn; PV contracts over the same permuted index on both operands).
__global__ __launch_bounds__(256) void k_vtrans(const __bf16* __restrict__ qkv,
                                                __bf16* __restrict__ vt) {
  __shared__ __align__(16) __bf16 tile[128 * 72];   // [s][d] padded stride 72
  int t = threadIdx.x;
  int bh = blockIdx.y, b = bh >> 4, h = bh & 15;
  int s0 = blockIdx.x * 128;
  const __bf16* src = qkv + (size_t)(b * SEQ + s0) * NQKV + h * 192 + 128;
#pragma unroll
  for (int i = 0; i < 4; i++) {
    int tt = i * 256 + t; int s = tt >> 3, ch = tt & 7;
    *(bf16x8*)(tile + s * 72 + ch * 8) = *(const bf16x8*)(src + (size_t)s * NQKV + ch * 8);
  }
  __syncthreads();
  __bf16* dst = vt + (size_t)bh * 64 * SEQ + s0;
#pragma unroll
  for (int i = 0; i < 4; i++) {
    int tt = i * 256 + t; int d = tt >> 4, w = tt & 15;
    bf16x8 o;
#pragma unroll
    for (int m = 0; m < 8; m++) o[m] = tile[(m * 16 + w) * 72 + d];   // s = m*16+w -> s' = w*8+m
    *(bf16x8*)(dst + (size_t)d * SEQ + w * 8) = o;
  }
}

// ---------------- fused flash attention, BARRIER-FREE ----------------
// K/V fragments read directly from global (L1/L2-resident, 16 full 64B lines
// per b128 gather, identical addresses across waves -> L1 reuse). Only the
// wave-private P round-trip uses LDS (32 KB total). Zero __syncthreads.
__global__ __launch_bounds__(256, 3) void k_attn(const __bf16* __restrict__ qkv,
                                                 const __bf16* __restrict__ vt,
                                                 __bf16* __restrict__ aout) {
  __shared__ __align__(16) __bf16 smem[16384];   // 32 KB: 4 x wave-private P
  const int t = threadIdx.x;
  const int lane = t & 63, wv = t >> 6;
  const int ln = lane & 15, quad = lane >> 4;
  __bf16* Ps = smem + wv * 4096;   // [32][128] swizzled

  int gid = blockIdx.x;
  int slot = gid & 7, j = gid >> 3;
  int bh = slot * 4 + (j >> 4);     // 4 (b,h) pairs per XCD slot -> K/V pinned in XCD L2
  int qt0 = j & 15;
  const int b = bh >> 4, h = bh & 15;
  const int q0 = qt0 * 128;

  const __bf16* qbase = qkv + (size_t)b * SEQ * NQKV + h * 192;
  const __bf16* kbase = qbase + 64;
  const __bf16* vbase = vt + (size_t)bh * 64 * SEQ;

  // Q fragments directly from global (one-time)
  bf16x8 qf[2][2];
#pragma unroll
  for (int qt = 0; qt < 2; qt++)
#pragma unroll
    for (int dc = 0; dc < 2; dc++)
      qf[qt][dc] = *(const bf16x8*)(qbase + (size_t)(q0 + wv * 32 + qt * 16 + ln) * NQKV + dc * 32 + quad * 8);

  const f32x4 zero4 = {0.f, 0.f, 0.f, 0.f};
  f32x4 O[2][4];
  float m_run[2][4], l_run[2][4];
#pragma unroll
  for (int qt = 0; qt < 2; qt++)
#pragma unroll
    for (int r = 0; r < 4; r++) { m_run[qt][r] = -__builtin_inff(); l_run[qt][r] = 0.f; }
#pragma unroll
  for (int qt = 0; qt < 2; qt++)
#pragma unroll
    for (int dt = 0; dt < 4; dt++) O[qt][dt] = zero4;

  const float CE = 0.125f * 1.44269504089f;  // scale * log2(e)

  for (int kt0 = 0; kt0 < SEQ; kt0 += 128) {
    // S = Q K^T  (K fragments straight from global; 16 lines x 64B per gather)
    f32x4 Sv[2][8];
#pragma unroll
    for (int kt = 0; kt < 8; kt++) {
      const __bf16* krow = kbase + (size_t)(kt0 + kt * 16 + ln) * NQKV + quad * 8;
      bf16x8 kf0 = *(const bf16x8*)(krow);
      bf16x8 kf1 = *(const bf16x8*)(krow + 32);
#pragma unroll
      for (int qt = 0; qt < 2; qt++) {
        f32x4 s = __builtin_amdgcn_mfma_f32_16x16x32_bf16(qf[qt][0], kf0, zero4, 0, 0, 0);
        s = __builtin_amdgcn_mfma_f32_16x16x32_bf16(qf[qt][1], kf1, s, 0, 0, 0);
        Sv[qt][kt] = s;
      }
    }
    // online softmax (hardware exp2)
    float nm[2][4];   // -m_new * CE
#pragma unroll
    for (int qt = 0; qt < 2; qt++)
#pragma unroll
      for (int r = 0; r < 4; r++) {
        float mx = Sv[qt][0][r];
#pragma unroll
        for (int kt = 1; kt < 8; kt++) mx = fmaxf(mx, Sv[qt][kt][r]);
        mx = fmaxf(mx, __shfl_xor(mx, 1));
        mx = fmaxf(mx, __shfl_xor(mx, 2));
        mx = fmaxf(mx, __shfl_xor(mx, 4));
        mx = fmaxf(mx, __shfl_xor(mx, 8));
        float mn = fmaxf(m_run[qt][r], mx);
        float alpha = fexp2((m_run[qt][r] - mn) * CE);
        m_run[qt][r] = mn;
        nm[qt][r] = -mn * CE;
        l_run[qt][r] *= alpha;
#pragma unroll
        for (int dt = 0; dt < 4; dt++) O[qt][dt][r] *= alpha;
      }
    // P = exp2(S*CE - m*CE), packed b128 store at k' = ln*8 + kt, XOR-(r&3)*32 swizzle
#pragma unroll
    for (int qt = 0; qt < 2; qt++)
#pragma unroll
      for (int r = 0; r < 4; r++) {
        float psum = 0.f;
        bf16x8 pk;
#pragma unroll
        for (int kt = 0; kt < 8; kt++) {
          float p = fexp2(__builtin_fmaf(Sv[qt][kt][r], CE, nm[qt][r]));
          psum += p;
          pk[kt] = f2bf(p);
        }
        *(bf16x8*)(Ps + (qt * 16 + quad * 4 + r) * 128 + ((ln * 8) ^ (r * 32))) = pk;
        l_run[qt][r] += psum;
      }
    // O += P V  (P from wave-private LDS, V fragments straight from global)
#pragma unroll
    for (int kc = 0; kc < 4; kc++) {
      bf16x8 pf0 = *(const bf16x8*)(Ps +  ln       * 128 + ((kc ^ (ln & 3)) * 32) + quad * 8);
      bf16x8 pf1 = *(const bf16x8*)(Ps + (16 + ln) * 128 + ((kc ^ (ln & 3)) * 32) + quad * 8);
#pragma unroll
      for (int dt = 0; dt < 4; dt++) {
        bf16x8 vf = *(const bf16x8*)(vbase + (size_t)(dt * 16 + ln) * SEQ + kt0 + kc * 32 + quad * 8);
        O[0][dt] = __builtin_amdgcn_mfma_f32_16x16x32_bf16(pf0, vf, O[0][dt], 0, 0, 0);
        O[1][dt] = __builtin_amdgcn_mfma_f32_16x16x32_bf16(pf1, vf, O[1][dt], 0, 0, 0);
      }
    }
  }
  // epilogue: O /= l, stage rows to wave-private LDS, coalesced 16B stores
#pragma unroll
  for (int qt = 0; qt < 2; qt++)
#pragma unroll
    for (int r = 0; r < 4; r++) {
      float l = l_run[qt][r];
      l += __shfl_xor(l, 1); l += __shfl_xor(l, 2);
      l += __shfl_xor(l, 4); l += __shfl_xor(l, 8);
      float inv = 1.0f / l;
#pragma unroll
      for (int dt = 0; dt < 4; dt++)
        Ps[(qt * 16 + quad * 4 + r) * 64 + dt * 16 + ln] = f2bf(O[qt][dt][r] * inv);
    }
  __bf16* obase = aout + (size_t)(b * SEQ + q0 + wv * 32) * HIDDEN + h * 64;
#pragma unroll
  for (int i = 0; i < 4; i++) {
    int tt = i * 64 + lane; int row = tt >> 3, ch = tt & 7;
    *(bf16x8*)(obase + (size_t)row * HIDDEN + ch * 8) = *(const bf16x8*)(Ps + row * 64 + ch * 8);
  }
}

extern "C" void kernel_launch(void* const* d_in, const int* in_sizes, int n_in,
                              void* d_out, int out_size, void* d_ws, size_t ws_size,
                              hipStream_t stream) {
  const float* x     = (const float*)d_in[0];
  const float* qkv_w = (const float*)d_in[1];
  const float* qkv_b = (const float*)d_in[2];
  const float* out_w = (const float*)d_in[3];
  const float* out_b = (const float*)d_in[4];

  char* ws = (char*)d_ws;
  __bf16* xb   = (__bf16*)(ws);                       // 4096*1024*2   =  8,388,608
  __bf16* wqkT = (__bf16*)(ws + 8388608);             // 3072*1024*2   =  6,291,456
  __bf16* woT  = (__bf16*)(ws + 14680064);            // 1024*1024*2   =  2,097,152
  __bf16* qkv  = (__bf16*)(ws + 16777216);            // 4096*3072*2   = 25,165,824
  __bf16* vt   = (__bf16*)(ws + 41943040);            // 32*64*2048*2  =  8,388,608
  __bf16* aout = (__bf16*)(ws + 50331648);            // 4096*1024*2   =  8,388,608

  k_convert_x<<<MTOT * HIDDEN / 1024, 256, 0, stream>>>(x, xb);
  k_transpose_w<<<dim3(NQKV / 64, HIDDEN / 64), 256, 0, stream>>>(qkv_w, wqkT, HIDDEN, NQKV);
  k_transpose_w<<<dim3(HIDDEN / 64, HIDDEN / 64), 256, 0, stream>>>(out_w, woT, HIDDEN, HIDDEN);
  k_gemm<1><<<dim3(NQKV / 128, MTOT / 128), 256, 0, stream>>>(xb, wqkT, qkv_b, qkv, MTOT, NQKV, HIDDEN);
  k_vtrans<<<dim3(SEQ / 128, 32), 256, 0, stream>>>(qkv, vt);
  k_attn<<<512, 256, 0, stream>>>(qkv, vt, aout);
  k_gemm<0><<<dim3(HIDDEN / 128, MTOT / 128), 256, 0, stream>>>(aout, woT, out_b, (float*)d_out, MTOT, HIDDEN, HIDDEN);
}

// Round 4
// 225.243 us; speedup vs baseline: 1.4238x; 1.4238x over previous
//
#include <hip/hip_runtime.h>
#include <hip/hip_bf16.h>
#include <cstdint>
#include <cstddef>

typedef float  f32x4  __attribute__((ext_vector_type(4)));
typedef __bf16 bf16x8 __attribute__((ext_vector_type(8)));
typedef __bf16 bf16x4 __attribute__((ext_vector_type(4)));

#define HIDDEN 1024
#define SEQ    2048
#define BATCH  2
#define NQKV   3072
#define MTOT   4096

__device__ __forceinline__ __bf16 f2bf(float f) {
  unsigned u = __builtin_bit_cast(unsigned, f);
  u += 0x7FFFu + ((u >> 16) & 1u);          // round-to-nearest-even
  unsigned short s = (unsigned short)(u >> 16);
  return __builtin_bit_cast(__bf16, s);
}

__device__ __forceinline__ float fexp2(float x) {
#if __has_builtin(__builtin_amdgcn_exp2f)
  return __builtin_amdgcn_exp2f(x);   // bare v_exp_f32
#else
  return exp2f(x);
#endif
}

__device__ __forceinline__ void async16(const void* g, void* l) {
  __builtin_amdgcn_global_load_lds((__attribute__((address_space(1))) void*)(g),
                                   (__attribute__((address_space(3))) void*)(l),
                                   16, 0, 0);
}

// ---------------- fp32 -> bf16 elementwise convert (x) ----------------
__global__ __launch_bounds__(256) void k_convert_x(const float* __restrict__ in,
                                                   __bf16* __restrict__ out) {
  int i = blockIdx.x * 256 + threadIdx.x;
  float4 v = ((const float4*)in)[i];
  bf16x4 o;
  o[0] = f2bf(v.x); o[1] = f2bf(v.y); o[2] = f2bf(v.z); o[3] = f2bf(v.w);
  ((bf16x4*)out)[i] = o;
}

// ---------------- W[K][N] fp32 -> WT[N][K] bf16 ----------------
__global__ __launch_bounds__(256) void k_transpose_w(const float* __restrict__ W,
                                                     __bf16* __restrict__ WT,
                                                     int K, int N) {
  __shared__ float tile[64][65];
  int tx = threadIdx.x & 63, ty = threadIdx.x >> 6;
  int n0 = blockIdx.x * 64, k0 = blockIdx.y * 64;
#pragma unroll
  for (int r = 0; r < 16; r++) {
    int row = r * 4 + ty;
    tile[row][tx] = W[(size_t)(k0 + row) * N + n0 + tx];
  }
  __syncthreads();
#pragma unroll
  for (int r = 0; r < 16; r++) {
    int row = r * 4 + ty;   // n index
    WT[(size_t)(n0 + row) * K + k0 + tx] = f2bf(tile[tx][row]);
  }
}

// ---------------- GEMM: C[M][N] = A[M][K] * BT[N][K]^T + bias ----------------
template <int BF16OUT>
__global__ __launch_bounds__(256) void k_gemm(const __bf16* __restrict__ A,
                                              const __bf16* __restrict__ BT,
                                              const float* __restrict__ bias,
                                              void* __restrict__ Cout,
                                              int M, int N, int K) {
  __shared__ __align__(16) __bf16 As[128 * 32];
  __shared__ __align__(16) __bf16 Bs[128 * 32];
  const int t = threadIdx.x;
  const int lane = t & 63, wv = t >> 6;
  const int ln = lane & 15, quad = lane >> 4;
  const int wm = (wv & 1) * 64, wn = (wv >> 1) * 64;
  const int m0 = blockIdx.y * 128, n0 = blockIdx.x * 128;

  const f32x4 zero4 = {0.f, 0.f, 0.f, 0.f};
  f32x4 acc[4][4];
#pragma unroll
  for (int i = 0; i < 4; i++)
#pragma unroll
    for (int j = 0; j < 4; j++) acc[i][j] = zero4;

  for (int k0 = 0; k0 < K; k0 += 32) {
    __syncthreads();
#pragma unroll
    for (int i = 0; i < 2; i++) {
      int tt = i * 256 + t;
      int row = tt >> 2, ch = tt & 3;
      async16(A  + (size_t)(m0 + row) * K + k0 + ch * 8, As + tt * 8);
      async16(BT + (size_t)(n0 + row) * K + k0 + ch * 8, Bs + tt * 8);
    }
    __syncthreads();
    bf16x8 af[4], bfr[4];
#pragma unroll
    for (int x = 0; x < 4; x++)
      af[x] = *(const bf16x8*)(As + (wm + x * 16 + ln) * 32 + quad * 8);
#pragma unroll
    for (int x = 0; x < 4; x++)
      bfr[x] = *(const bf16x8*)(Bs + (wn + x * 16 + ln) * 32 + quad * 8);
#pragma unroll
    for (int mt = 0; mt < 4; mt++)
#pragma unroll
      for (int nt = 0; nt < 4; nt++)
        acc[mt][nt] = __builtin_amdgcn_mfma_f32_16x16x32_bf16(af[mt], bfr[nt], acc[mt][nt], 0, 0, 0);
  }
#pragma unroll
  for (int nt = 0; nt < 4; nt++) {
    int col = n0 + wn + nt * 16 + ln;
    float bv = bias[col];
#pragma unroll
    for (int mt = 0; mt < 4; mt++) {
#pragma unroll
      for (int r = 0; r < 4; r++) {
        int row = m0 + wm + mt * 16 + quad * 4 + r;
        float v = acc[mt][nt][r] + bv;
        if (BF16OUT) ((__bf16*)Cout)[(size_t)row * N + col] = f2bf(v);
        else         ((float*)Cout)[(size_t)row * N + col] = v;
      }
    }
  }
}

// ---------------- V slice of qkv -> vt[bh][d=64][s' permuted] ----------------
// Within each 128-wide s-block: s' = (s&15)*8 + (s>>4)  (matches P-store layout
// in k_attn; PV contracts over the same permuted index on both operands).
__global__ __launch_bounds__(256) void k_vtrans(const __bf16* __restrict__ qkv,
                                                __bf16* __restrict__ vt) {
  __shared__ __align__(16) __bf16 tile[128 * 72];   // [s][d] padded stride 72
  int t = threadIdx.x;
  int bh = blockIdx.y, b = bh >> 4, h = bh & 15;
  int s0 = blockIdx.x * 128;
  const __bf16* src = qkv + (size_t)(b * SEQ + s0) * NQKV + h * 192 + 128;
#pragma unroll
  for (int i = 0; i < 4; i++) {
    int tt = i * 256 + t; int s = tt >> 3, ch = tt & 7;
    *(bf16x8*)(tile + s * 72 + ch * 8) = *(const bf16x8*)(src + (size_t)s * NQKV + ch * 8);
  }
  __syncthreads();
  __bf16* dst = vt + (size_t)bh * 64 * SEQ + s0;
#pragma unroll
  for (int i = 0; i < 4; i++) {
    int tt = i * 256 + t; int d = tt >> 4, w = tt & 15;
    bf16x8 o;
#pragma unroll
    for (int m = 0; m < 8; m++) o[m] = tile[(m * 16 + w) * 72 + d];   // s = m*16+w -> s' = w*8+m
    *(bf16x8*)(dst + (size_t)d * SEQ + w * 8) = o;
  }
}

// ---------------- fused flash attention, double-buffered K pipeline ----------------
// LDS 80 KB: Kbuf 2 x [2 d-half][128][32] (32K), Vs [4 chunk][64][32] (16K),
// Ps 4 x wave-private [32][128] swizzled (32K). 2 blocks/CU.
// Pipeline: issue K(i+1) + V(i) at loop top; S+softmax+P-pack overlap their
// flight; mid-barrier drain is covered; end barrier protects buffer reuse.
__global__ __launch_bounds__(256, 2) void k_attn(const __bf16* __restrict__ qkv,
                                                 const __bf16* __restrict__ vt,
                                                 __bf16* __restrict__ aout) {
  __shared__ __align__(16) __bf16 smem[40960];   // 80 KB
  const int t = threadIdx.x;
  const int lane = t & 63, wv = t >> 6;
  const int ln = lane & 15, quad = lane >> 4;
  __bf16* Vs = smem + 16384;
  __bf16* Ps = smem + 24576 + wv * 4096;   // [32][128] swizzled, wave-private

  int gid = blockIdx.x;
  int slot = gid & 7, j = gid >> 3;
  int bh = slot * 4 + (j >> 4);     // 4 (b,h) pairs per XCD slot -> K/V pinned in XCD L2
  int qt0 = j & 15;
  const int b = bh >> 4, h = bh & 15;
  const int q0 = qt0 * 128;

  const __bf16* qbase = qkv + (size_t)b * SEQ * NQKV + h * 192;
  const __bf16* kbase = qbase + 64;
  const __bf16* vbase = vt + (size_t)bh * 64 * SEQ;

  // prologue: stage K(0) into Kbuf0
  {
    __bf16* Kd = smem;
#pragma unroll
    for (int i = 0; i < 4; i++) {
      int tt = i * 256 + t;
      int hh = tt >> 9, row = (tt >> 2) & 127, ch = tt & 3;
      async16(kbase + (size_t)row * NQKV + hh * 32 + ch * 8, Kd + tt * 8);
    }
  }

  // Q fragments directly from global (one-time)
  bf16x8 qf[2][2];
#pragma unroll
  for (int qt = 0; qt < 2; qt++)
#pragma unroll
    for (int dc = 0; dc < 2; dc++)
      qf[qt][dc] = *(const bf16x8*)(qbase + (size_t)(q0 + wv * 32 + qt * 16 + ln) * NQKV + dc * 32 + quad * 8);

  const f32x4 zero4 = {0.f, 0.f, 0.f, 0.f};
  f32x4 O[2][4];
  float m_run[2][4], l_run[2][4];
#pragma unroll
  for (int qt = 0; qt < 2; qt++)
#pragma unroll
    for (int r = 0; r < 4; r++) { m_run[qt][r] = -__builtin_inff(); l_run[qt][r] = 0.f; }
#pragma unroll
  for (int qt = 0; qt < 2; qt++)
#pragma unroll
    for (int dt = 0; dt < 4; dt++) O[qt][dt] = zero4;

  const float CE = 0.125f * 1.44269504089f;  // scale * log2(e)

  __syncthreads();   // K(0) landed

  for (int it = 0; it < SEQ / 128; it++) {
    const int kt0 = it * 128;
    const __bf16* Kcur = smem + (it & 1) * 8192;
    // prefetch K(it+1) into other buffer — flies through S+softmax
    if (it + 1 < SEQ / 128) {
      __bf16* Kd = smem + ((it + 1) & 1) * 8192;
      const __bf16* kn = kbase + (size_t)(kt0 + 128) * NQKV;
#pragma unroll
      for (int i = 0; i < 4; i++) {
        int tt = i * 256 + t;
        int hh = tt >> 9, row = (tt >> 2) & 127, ch = tt & 3;
        async16(kn + (size_t)row * NQKV + hh * 32 + ch * 8, Kd + tt * 8);
      }
    }
    // stage V(it) — consumed after mid-barrier, flies through S+softmax
#pragma unroll
    for (int i = 0; i < 4; i++) {
      int tt = i * 256 + t;
      int c = tt >> 8, d = (tt >> 2) & 63, w = tt & 3;
      async16(vbase + (size_t)d * SEQ + kt0 + c * 32 + w * 8, Vs + tt * 8);
    }

    // S = Q K^T from Kcur (landed: previous iteration's barrier drained it)
    f32x4 Sv[2][8];
#pragma unroll
    for (int kt = 0; kt < 8; kt++) {
      bf16x8 kf0 = *(const bf16x8*)(Kcur +        (kt * 16 + ln) * 32 + quad * 8);
      bf16x8 kf1 = *(const bf16x8*)(Kcur + 4096 + (kt * 16 + ln) * 32 + quad * 8);
#pragma unroll
      for (int qt = 0; qt < 2; qt++) {
        f32x4 s = __builtin_amdgcn_mfma_f32_16x16x32_bf16(qf[qt][0], kf0, zero4, 0, 0, 0);
        s = __builtin_amdgcn_mfma_f32_16x16x32_bf16(qf[qt][1], kf1, s, 0, 0, 0);
        Sv[qt][kt] = s;
      }
    }
    // online softmax (hardware exp2)
    float nm[2][4];   // -m_new * CE
#pragma unroll
    for (int qt = 0; qt < 2; qt++)
#pragma unroll
      for (int r = 0; r < 4; r++) {
        float mx = Sv[qt][0][r];
#pragma unroll
        for (int kt = 1; kt < 8; kt++) mx = fmaxf(mx, Sv[qt][kt][r]);
        mx = fmaxf(mx, __shfl_xor(mx, 1));
        mx = fmaxf(mx, __shfl_xor(mx, 2));
        mx = fmaxf(mx, __shfl_xor(mx, 4));
        mx = fmaxf(mx, __shfl_xor(mx, 8));
        float mn = fmaxf(m_run[qt][r], mx);
        float alpha = fexp2((m_run[qt][r] - mn) * CE);
        m_run[qt][r] = mn;
        nm[qt][r] = -mn * CE;
        l_run[qt][r] *= alpha;
#pragma unroll
        for (int dt = 0; dt < 4; dt++) O[qt][dt][r] *= alpha;
      }
    // P = exp2(S*CE - m*CE), packed b128 store at k' = ln*8 + kt, XOR-(r&3)*32 swizzle
#pragma unroll
    for (int qt = 0; qt < 2; qt++)
#pragma unroll
      for (int r = 0; r < 4; r++) {
        float psum = 0.f;
        bf16x8 pk;
#pragma unroll
        for (int kt = 0; kt < 8; kt++) {
          float p = fexp2(__builtin_fmaf(Sv[qt][kt][r], CE, nm[qt][r]));
          psum += p;
          pk[kt] = f2bf(p);
        }
        *(bf16x8*)(Ps + (qt * 16 + quad * 4 + r) * 128 + ((ln * 8) ^ (r * 32))) = pk;
        l_run[qt][r] += psum;
      }

    __syncthreads();   // V(it) + K(it+1) landed; P visible to own wave

    // O += P V  over permuted k' (both operands permuted identically)
#pragma unroll
    for (int kc = 0; kc < 4; kc++) {
      bf16x8 pf0 = *(const bf16x8*)(Ps +  ln       * 128 + ((kc ^ (ln & 3)) * 32) + quad * 8);
      bf16x8 pf1 = *(const bf16x8*)(Ps + (16 + ln) * 128 + ((kc ^ (ln & 3)) * 32) + quad * 8);
#pragma unroll
      for (int dt = 0; dt < 4; dt++) {
        bf16x8 vf = *(const bf16x8*)(Vs + kc * 2048 + (dt * 16 + ln) * 32 + quad * 8);
        O[0][dt] = __builtin_amdgcn_mfma_f32_16x16x32_bf16(pf0, vf, O[0][dt], 0, 0, 0);
        O[1][dt] = __builtin_amdgcn_mfma_f32_16x16x32_bf16(pf1, vf, O[1][dt], 0, 0, 0);
      }
    }

    __syncthreads();   // Vs / Kcur free for next iteration's staging
  }
  // epilogue: O /= l, stage rows to wave-private LDS, coalesced 16B stores
#pragma unroll
  for (int qt = 0; qt < 2; qt++)
#pragma unroll
    for (int r = 0; r < 4; r++) {
      float l = l_run[qt][r];
      l += __shfl_xor(l, 1); l += __shfl_xor(l, 2);
      l += __shfl_xor(l, 4); l += __shfl_xor(l, 8);
      float inv = 1.0f / l;
#pragma unroll
      for (int dt = 0; dt < 4; dt++)
        Ps[(qt * 16 + quad * 4 + r) * 64 + dt * 16 + ln] = f2bf(O[qt][dt][r] * inv);
    }
  __bf16* obase = aout + (size_t)(b * SEQ + q0 + wv * 32) * HIDDEN + h * 64;
#pragma unroll
  for (int i = 0; i < 4; i++) {
    int tt = i * 64 + lane; int row = tt >> 3, ch = tt & 7;
    *(bf16x8*)(obase + (size_t)row * HIDDEN + ch * 8) = *(const bf16x8*)(Ps + row * 64 + ch * 8);
  }
}

extern "C" void kernel_launch(void* const* d_in, const int* in_sizes, int n_in,
                              void* d_out, int out_size, void* d_ws, size_t ws_size,
                              hipStream_t stream) {
  const float* x     = (const float*)d_in[0];
  const float* qkv_w = (const float*)d_in[1];
  const float* qkv_b = (const float*)d_in[2];
  const float* out_w = (const float*)d_in[3];
  const float* out_b = (const float*)d_in[4];

  char* ws = (char*)d_ws;
  __bf16* xb   = (__bf16*)(ws);                       // 4096*1024*2   =  8,388,608
  __bf16* wqkT = (__bf16*)(ws + 8388608);             // 3072*1024*2   =  6,291,456
  __bf16* woT  = (__bf16*)(ws + 14680064);            // 1024*1024*2   =  2,097,152
  __bf16* qkv  = (__bf16*)(ws + 16777216);            // 4096*3072*2   = 25,165,824
  __bf16* vt   = (__bf16*)(ws + 41943040);            // 32*64*2048*2  =  8,388,608
  __bf16* aout = (__bf16*)(ws + 50331648);            // 4096*1024*2   =  8,388,608

  k_convert_x<<<MTOT * HIDDEN / 1024, 256, 0, stream>>>(x, xb);
  k_transpose_w<<<dim3(NQKV / 64, HIDDEN / 64), 256, 0, stream>>>(qkv_w, wqkT, HIDDEN, NQKV);
  k_transpose_w<<<dim3(HIDDEN / 64, HIDDEN / 64), 256, 0, stream>>>(out_w, woT, HIDDEN, HIDDEN);
  k_gemm<1><<<dim3(NQKV / 128, MTOT / 128), 256, 0, stream>>>(xb, wqkT, qkv_b, qkv, MTOT, NQKV, HIDDEN);
  k_vtrans<<<dim3(SEQ / 128, 32), 256, 0, stream>>>(qkv, vt);
  k_attn<<<512, 256, 0, stream>>>(qkv, vt, aout);
  k_gemm<0><<<dim3(HIDDEN / 128, MTOT / 128), 256, 0, stream>>>(aout, woT, out_b, (float*)d_out, MTOT, HIDDEN, HIDDEN);
}

// Round 5
// 208.614 us; speedup vs baseline: 1.5373x; 1.0797x over previous
//
#include <hip/hip_runtime.h>
#include <hip/hip_bf16.h>
#include <cstdint>
#include <cstddef>

typedef float  f32x4  __attribute__((ext_vector_type(4)));
typedef __bf16 bf16x8 __attribute__((ext_vector_type(8)));
typedef __bf16 bf16x4 __attribute__((ext_vector_type(4)));

#define HIDDEN 1024
#define SEQ    2048
#define BATCH  2
#define NQKV   3072
#define MTOT   4096

__device__ __forceinline__ __bf16 f2bf(float f) {
  unsigned u = __builtin_bit_cast(unsigned, f);
  u += 0x7FFFu + ((u >> 16) & 1u);          // round-to-nearest-even
  unsigned short s = (unsigned short)(u >> 16);
  return __builtin_bit_cast(__bf16, s);
}

// pack two f32 -> bf16x2 (round-half-up) in 3 VALU: 2 adds + 1 v_perm_b32
__device__ __forceinline__ unsigned pk2(float a, float b) {
  unsigned ua = __builtin_bit_cast(unsigned, a) + 0x8000u;
  unsigned ub = __builtin_bit_cast(unsigned, b) + 0x8000u;
  return __builtin_amdgcn_perm(ub, ua, 0x07060302u);  // {hi16(ub), hi16(ua)}
}

__device__ __forceinline__ float fexp2(float x) {
#if __has_builtin(__builtin_amdgcn_exp2f)
  return __builtin_amdgcn_exp2f(x);   // bare v_exp_f32
#else
  return exp2f(x);
#endif
}

__device__ __forceinline__ void async16(const void* g, void* l) {
  __builtin_amdgcn_global_load_lds((__attribute__((address_space(1))) void*)(g),
                                   (__attribute__((address_space(3))) void*)(l),
                                   16, 0, 0);
}

// ---------------- fp32 -> bf16 elementwise convert (x) ----------------
__global__ __launch_bounds__(256) void k_convert_x(const float* __restrict__ in,
                                                   __bf16* __restrict__ out) {
  int i = blockIdx.x * 256 + threadIdx.x;
  float4 v = ((const float4*)in)[i];
  bf16x4 o;
  o[0] = f2bf(v.x); o[1] = f2bf(v.y); o[2] = f2bf(v.z); o[3] = f2bf(v.w);
  ((bf16x4*)out)[i] = o;
}

// ---------------- W[K][N] fp32 -> WT[N][K] bf16 ----------------
__global__ __launch_bounds__(256) void k_transpose_w(const float* __restrict__ W,
                                                     __bf16* __restrict__ WT,
                                                     int K, int N) {
  __shared__ float tile[64][65];
  int tx = threadIdx.x & 63, ty = threadIdx.x >> 6;
  int n0 = blockIdx.x * 64, k0 = blockIdx.y * 64;
#pragma unroll
  for (int r = 0; r < 16; r++) {
    int row = r * 4 + ty;
    tile[row][tx] = W[(size_t)(k0 + row) * N + n0 + tx];
  }
  __syncthreads();
#pragma unroll
  for (int r = 0; r < 16; r++) {
    int row = r * 4 + ty;   // n index
    WT[(size_t)(n0 + row) * K + k0 + tx] = f2bf(tile[tx][row]);
  }
}

// ---------------- GEMM: C[M][N] = A[M][K] * BT[N][K]^T + bias ----------------
template <int BF16OUT>
__global__ __launch_bounds__(256) void k_gemm(const __bf16* __restrict__ A,
                                              const __bf16* __restrict__ BT,
                                              const float* __restrict__ bias,
                                              void* __restrict__ Cout,
                                              int M, int N, int K) {
  __shared__ __align__(16) __bf16 As[128 * 32];
  __shared__ __align__(16) __bf16 Bs[128 * 32];
  const int t = threadIdx.x;
  const int lane = t & 63, wv = t >> 6;
  const int ln = lane & 15, quad = lane >> 4;
  const int wm = (wv & 1) * 64, wn = (wv >> 1) * 64;
  const int m0 = blockIdx.y * 128, n0 = blockIdx.x * 128;

  const f32x4 zero4 = {0.f, 0.f, 0.f, 0.f};
  f32x4 acc[4][4];
#pragma unroll
  for (int i = 0; i < 4; i++)
#pragma unroll
    for (int j = 0; j < 4; j++) acc[i][j] = zero4;

  for (int k0 = 0; k0 < K; k0 += 32) {
    __syncthreads();
#pragma unroll
    for (int i = 0; i < 2; i++) {
      int tt = i * 256 + t;
      int row = tt >> 2, ch = tt & 3;
      async16(A  + (size_t)(m0 + row) * K + k0 + ch * 8, As + tt * 8);
      async16(BT + (size_t)(n0 + row) * K + k0 + ch * 8, Bs + tt * 8);
    }
    __syncthreads();
    bf16x8 af[4], bfr[4];
#pragma unroll
    for (int x = 0; x < 4; x++)
      af[x] = *(const bf16x8*)(As + (wm + x * 16 + ln) * 32 + quad * 8);
#pragma unroll
    for (int x = 0; x < 4; x++)
      bfr[x] = *(const bf16x8*)(Bs + (wn + x * 16 + ln) * 32 + quad * 8);
#pragma unroll
    for (int mt = 0; mt < 4; mt++)
#pragma unroll
      for (int nt = 0; nt < 4; nt++)
        acc[mt][nt] = __builtin_amdgcn_mfma_f32_16x16x32_bf16(af[mt], bfr[nt], acc[mt][nt], 0, 0, 0);
  }
#pragma unroll
  for (int nt = 0; nt < 4; nt++) {
    int col = n0 + wn + nt * 16 + ln;
    float bv = bias[col];
#pragma unroll
    for (int mt = 0; mt < 4; mt++) {
#pragma unroll
      for (int r = 0; r < 4; r++) {
        int row = m0 + wm + mt * 16 + quad * 4 + r;
        float v = acc[mt][nt][r] + bv;
        if (BF16OUT) ((__bf16*)Cout)[(size_t)row * N + col] = f2bf(v);
        else         ((float*)Cout)[(size_t)row * N + col] = v;
      }
    }
  }
}

// ---------------- V slice of qkv -> vt[bh][d=64][s' permuted] ----------------
// Within each 128-wide s-block, position p stores original s = g(p):
//   kc=p>>5, q2=(p>>3)&3, j=p&7  ->  s = (kc + (j>>2)*4)*16 + q2*4 + (j&3)
// This matches k_attn's register-resident P layout (S^T C-layout -> A-frag reindex).
__global__ __launch_bounds__(256) void k_vtrans(const __bf16* __restrict__ qkv,
                                                __bf16* __restrict__ vt) {
  __shared__ __align__(16) __bf16 tile[128 * 72];   // [s][d] padded stride 72
  int t = threadIdx.x;
  int bh = blockIdx.y, b = bh >> 4, h = bh & 15;
  int s0 = blockIdx.x * 128;
  const __bf16* src = qkv + (size_t)(b * SEQ + s0) * NQKV + h * 192 + 128;
#pragma unroll
  for (int i = 0; i < 4; i++) {
    int tt = i * 256 + t; int s = tt >> 3, ch = tt & 7;
    *(bf16x8*)(tile + s * 72 + ch * 8) = *(const bf16x8*)(src + (size_t)s * NQKV + ch * 8);
  }
  __syncthreads();
  __bf16* dst = vt + (size_t)bh * 64 * SEQ + s0;
#pragma unroll
  for (int i = 0; i < 4; i++) {
    int tt = i * 256 + t; int d = tt >> 4, u = tt & 15;   // p0 = u*8
    int kc = u >> 2, q2 = u & 3;
    int sb = kc * 16 + q2 * 4;
    bf16x8 o;
#pragma unroll
    for (int j = 0; j < 8; j++) o[j] = tile[(sb + (j >> 2) * 64 + (j & 3)) * 72 + d];
    *(bf16x8*)(dst + (size_t)d * SEQ + u * 8) = o;
  }
}

// ---------------- fused flash attention: S^T dataflow, P in registers ----------------
// S^T = K*Q^T so each lane's scores share one q (col=ln); softmax reduces in-reg +
// xor16/32; P re-enters PV as A-frags by register reindex (permuted-k, V matches).
// LDS 64KB: K dbuf 2x16K + V dbuf 2x16K. One barrier per k-tile.
__global__ __launch_bounds__(256, 2) void k_attn(const __bf16* __restrict__ qkv,
                                                 const __bf16* __restrict__ vt,
                                                 __bf16* __restrict__ aout) {
  __shared__ __align__(16) __bf16 smem[32768];   // 64 KB
  const int t = threadIdx.x;
  const int lane = t & 63, wv = t >> 6;
  const int ln = lane & 15, quad = lane >> 4;

  int gid = blockIdx.x;
  int slot = gid & 7, j = gid >> 3;
  int bh = slot * 4 + (j >> 4);     // 4 (b,h) pairs per XCD slot -> K/V pinned in XCD L2
  int qt0 = j & 15;
  const int b = bh >> 4, h = bh & 15;
  const int q0 = qt0 * 128;

  const __bf16* qbase = qkv + (size_t)b * SEQ * NQKV + h * 192;
  const __bf16* kbase = qbase + 64;
  const __bf16* vbase = vt + (size_t)bh * 64 * SEQ;

  // prologue: stage K(0), V(0) into parity-0 buffers
#pragma unroll
  for (int i = 0; i < 4; i++) {
    int tt = i * 256 + t;
    int hh = tt >> 9, row = (tt >> 2) & 127, ch = tt & 3;
    async16(kbase + (size_t)row * NQKV + hh * 32 + ch * 8, smem + tt * 8);
  }
#pragma unroll
  for (int i = 0; i < 4; i++) {
    int tt = i * 256 + t;
    int c = tt >> 8, d = (tt >> 2) & 63, w = tt & 3;
    async16(vbase + (size_t)d * SEQ + c * 32 + w * 8, smem + 16384 + tt * 8);
  }

  // Q fragments directly from global (one-time); B-operand layout
  bf16x8 qf[2][2];
#pragma unroll
  for (int qt = 0; qt < 2; qt++)
#pragma unroll
    for (int dc = 0; dc < 2; dc++)
      qf[qt][dc] = *(const bf16x8*)(qbase + (size_t)(q0 + wv * 32 + qt * 16 + ln) * NQKV + dc * 32 + quad * 8);

  const f32x4 zero4 = {0.f, 0.f, 0.f, 0.f};
  f32x4 O[2][4];
  float m_run[2], l_run[2];
#pragma unroll
  for (int qt = 0; qt < 2; qt++) { m_run[qt] = -__builtin_inff(); l_run[qt] = 0.f; }
#pragma unroll
  for (int qt = 0; qt < 2; qt++)
#pragma unroll
    for (int dt = 0; dt < 4; dt++) O[qt][dt] = zero4;

  const float CE = 0.125f * 1.44269504089f;  // scale * log2(e)

  for (int it = 0; it < SEQ / 128; it++) {
    __syncthreads();   // K(it)/V(it) landed (issued last iter); prev buffers free
    const __bf16* Kcur = smem + (it & 1) * 8192;
    const __bf16* Vcur = smem + 16384 + (it & 1) * 8192;
    if (it + 1 < SEQ / 128) {   // prefetch next tile into other parity; flies over compute
      __bf16* Kd = smem + ((it + 1) & 1) * 8192;
      __bf16* Vd = smem + 16384 + ((it + 1) & 1) * 8192;
      const __bf16* kn = kbase + (size_t)(it + 1) * 128 * NQKV;
      const __bf16* vn = vbase + (it + 1) * 128;
#pragma unroll
      for (int i = 0; i < 4; i++) {
        int tt = i * 256 + t;
        int hh = tt >> 9, row = (tt >> 2) & 127, ch = tt & 3;
        async16(kn + (size_t)row * NQKV + hh * 32 + ch * 8, Kd + tt * 8);
      }
#pragma unroll
      for (int i = 0; i < 4; i++) {
        int tt = i * 256 + t;
        int c = tt >> 8, d = (tt >> 2) & 63, w = tt & 3;
        async16(vn + (size_t)d * SEQ + c * 32 + w * 8, Vd + tt * 8);
      }
    }

    // S^T = K * Q^T : A = K-frag (m = k-seq), B = Q-frag (n = q)
    // Sv[qt][blk][r] = S[k = blk*16 + quad*4 + r][q = qt*16 + ln]
    f32x4 Sv[2][8];
#pragma unroll
    for (int blk = 0; blk < 8; blk++) {
      bf16x8 kf0 = *(const bf16x8*)(Kcur +        (blk * 16 + ln) * 32 + quad * 8);
      bf16x8 kf1 = *(const bf16x8*)(Kcur + 4096 + (blk * 16 + ln) * 32 + quad * 8);
#pragma unroll
      for (int qt = 0; qt < 2; qt++) {
        f32x4 s = __builtin_amdgcn_mfma_f32_16x16x32_bf16(kf0, qf[qt][0], zero4, 0, 0, 0);
        s = __builtin_amdgcn_mfma_f32_16x16x32_bf16(kf1, qf[qt][1], s, 0, 0, 0);
        Sv[qt][qt ? blk : blk] = s;  // placate sequencing; Sv[qt][blk]
        Sv[qt][blk] = s;
      }
    }

    float arow[2][4];   // alpha broadcast to row-layout, filled below
#pragma unroll
    for (int qt = 0; qt < 2; qt++) {
      // row-max over 32 in-reg values + cross-quad reduce
      f32x4 vm = Sv[qt][0];
#pragma unroll
      for (int blk = 1; blk < 8; blk++)
#pragma unroll
        for (int r = 0; r < 4; r++) vm[r] = fmaxf(vm[r], Sv[qt][blk][r]);
      float mx = fmaxf(fmaxf(vm[0], vm[1]), fmaxf(vm[2], vm[3]));
      mx = fmaxf(mx, __shfl_xor(mx, 16));
      mx = fmaxf(mx, __shfl_xor(mx, 32));
      float mn = fmaxf(m_run[qt], mx);
      float al = fexp2((m_run[qt] - mn) * CE);
      m_run[qt] = mn;
      float nm = -mn * CE;
      // P = exp2(S*CE + nm) in place; accumulate row-sum
      float psum = 0.f;
#pragma unroll
      for (int blk = 0; blk < 8; blk++)
#pragma unroll
        for (int r = 0; r < 4; r++) {
          float p = fexp2(__builtin_fmaf(Sv[qt][blk][r], CE, nm));
          Sv[qt][blk][r] = p;
          psum += p;
        }
      psum += __shfl_xor(psum, 16);
      psum += __shfl_xor(psum, 32);
      l_run[qt] = l_run[qt] * al + psum;
      // broadcast alpha to row-layout (O rows are q = quad*4 + r)
#pragma unroll
      for (int r = 0; r < 4; r++) arow[qt][r] = __shfl(al, quad * 4 + r);
#pragma unroll
      for (int dt = 0; dt < 4; dt++)
#pragma unroll
        for (int r = 0; r < 4; r++) O[qt][dt][r] *= arow[qt][r];
    }

    // O += P*V : P packed from registers (permuted-k contraction, V pre-permuted)
#pragma unroll
    for (int kc = 0; kc < 4; kc++) {
      union { bf16x8 v; unsigned u[4]; } pf0, pf1;
      pf0.u[0] = pk2(Sv[0][kc][0],     Sv[0][kc][1]);
      pf0.u[1] = pk2(Sv[0][kc][2],     Sv[0][kc][3]);
      pf0.u[2] = pk2(Sv[0][kc + 4][0], Sv[0][kc + 4][1]);
      pf0.u[3] = pk2(Sv[0][kc + 4][2], Sv[0][kc + 4][3]);
      pf1.u[0] = pk2(Sv[1][kc][0],     Sv[1][kc][1]);
      pf1.u[1] = pk2(Sv[1][kc][2],     Sv[1][kc][3]);
      pf1.u[2] = pk2(Sv[1][kc + 4][0], Sv[1][kc + 4][1]);
      pf1.u[3] = pk2(Sv[1][kc + 4][2], Sv[1][kc + 4][3]);
#pragma unroll
      for (int dt = 0; dt < 4; dt++) {
        bf16x8 vf = *(const bf16x8*)(Vcur + kc * 2048 + (dt * 16 + ln) * 32 + quad * 8);
        O[0][dt] = __builtin_amdgcn_mfma_f32_16x16x32_bf16(pf0.v, vf, O[0][dt], 0, 0, 0);
        O[1][dt] = __builtin_amdgcn_mfma_f32_16x16x32_bf16(pf1.v, vf, O[1][dt], 0, 0, 0);
      }
    }
  }

  // epilogue: O /= l (l uniform across quads), stage to Kbuf0 region (dead), store
  __bf16* stage = smem + wv * 2048;
#pragma unroll
  for (int qt = 0; qt < 2; qt++) {
    float inv = 1.0f / l_run[qt];
#pragma unroll
    for (int r = 0; r < 4; r++) {
      float ir = __shfl(inv, quad * 4 + r);
#pragma unroll
      for (int dt = 0; dt < 4; dt++)
        stage[(qt * 16 + quad * 4 + r) * 64 + dt * 16 + ln] = f2bf(O[qt][dt][r] * ir);
    }
  }
  __bf16* obase = aout + (size_t)(b * SEQ + q0 + wv * 32) * HIDDEN + h * 64;
#pragma unroll
  for (int i = 0; i < 4; i++) {
    int tt = i * 64 + lane; int row = tt >> 3, ch = tt & 7;
    *(bf16x8*)(obase + (size_t)row * HIDDEN + ch * 8) = *(const bf16x8*)(stage + row * 64 + ch * 8);
  }
}

extern "C" void kernel_launch(void* const* d_in, const int* in_sizes, int n_in,
                              void* d_out, int out_size, void* d_ws, size_t ws_size,
                              hipStream_t stream) {
  const float* x     = (const float*)d_in[0];
  const float* qkv_w = (const float*)d_in[1];
  const float* qkv_b = (const float*)d_in[2];
  const float* out_w = (const float*)d_in[3];
  const float* out_b = (const float*)d_in[4];

  char* ws = (char*)d_ws;
  __bf16* xb   = (__bf16*)(ws);                       // 4096*1024*2   =  8,388,608
  __bf16* wqkT = (__bf16*)(ws + 8388608);             // 3072*1024*2   =  6,291,456
  __bf16* woT  = (__bf16*)(ws + 14680064);            // 1024*1024*2   =  2,097,152
  __bf16* qkv  = (__bf16*)(ws + 16777216);            // 4096*3072*2   = 25,165,824
  __bf16* vt   = (__bf16*)(ws + 41943040);            // 32*64*2048*2  =  8,388,608
  __bf16* aout = (__bf16*)(ws + 50331648);            // 4096*1024*2   =  8,388,608

  k_convert_x<<<MTOT * HIDDEN / 1024, 256, 0, stream>>>(x, xb);
  k_transpose_w<<<dim3(NQKV / 64, HIDDEN / 64), 256, 0, stream>>>(qkv_w, wqkT, HIDDEN, NQKV);
  k_transpose_w<<<dim3(HIDDEN / 64, HIDDEN / 64), 256, 0, stream>>>(out_w, woT, HIDDEN, HIDDEN);
  k_gemm<1><<<dim3(NQKV / 128, MTOT / 128), 256, 0, stream>>>(xb, wqkT, qkv_b, qkv, MTOT, NQKV, HIDDEN);
  k_vtrans<<<dim3(SEQ / 128, 32), 256, 0, stream>>>(qkv, vt);
  k_attn<<<512, 256, 0, stream>>>(qkv, vt, aout);
  k_gemm<0><<<dim3(HIDDEN / 128, MTOT / 128), 256, 0, stream>>>(aout, woT, out_b, (float*)d_out, MTOT, HIDDEN, HIDDEN);
}